// Round 5
// baseline (1835.786 us; speedup 1.0000x reference)
//
#include <hip/hip_runtime.h>
#include <math.h>

#define SEQ 197
#define EMB 768
#define NH  12
#define HD  64
#define NE  28

typedef __attribute__((ext_vector_type(8))) __bf16 bf16x8;
typedef __attribute__((ext_vector_type(4))) float  f32x4;

__device__ __forceinline__ unsigned short f2bf(float f) {
    unsigned u = __float_as_uint(f);
    u += 0x7fffu + ((u >> 16) & 1u);
    return (unsigned short)(u >> 16);
}
__device__ __forceinline__ float bfl(unsigned u) { return __uint_as_float(u << 16); }
__device__ __forceinline__ float bfh(unsigned u) { return __uint_as_float(u & 0xffff0000u); }
__device__ __forceinline__ void unpk8(uint4 v, float* f) {
    f[0]=bfl(v.x); f[1]=bfh(v.x); f[2]=bfl(v.y); f[3]=bfh(v.y);
    f[4]=bfl(v.z); f[5]=bfh(v.z); f[6]=bfl(v.w); f[7]=bfh(v.w);
}

__device__ __forceinline__ void gl_lds16(const ushort* g, ushort* l) {
    __builtin_amdgcn_global_load_lds(
        (const __attribute__((address_space(1))) unsigned int*)g,
        (__attribute__((address_space(3))) unsigned int*)l, 16, 0, 0);
}

// ---------------------------------------------------------------------------
// fp32 -> bf16 converters
// ---------------------------------------------------------------------------
__global__ void cvt_k(const float* __restrict__ src, ushort* __restrict__ dst, int n4) {
    int i = blockIdx.x * 256 + threadIdx.x;
    if (i < n4) {
        float4 v = ((const float4*)src)[i];
        ushort4 o = { f2bf(v.x), f2bf(v.y), f2bf(v.z), f2bf(v.w) };
        ((ushort4*)dst)[i] = o;
    }
}

__global__ void cvt_w4(const float* __restrict__ wq, const float* __restrict__ wk,
                       const float* __restrict__ wv, const float* __restrict__ wo,
                       ushort* __restrict__ wqkv, ushort* __restrict__ wob) {
    int i = blockIdx.x * 256 + threadIdx.x;          // 4 * 147456 total
    if (i >= 4 * 147456) return;
    int seg = i / 147456, r = i - seg * 147456;
    const float* s = (seg == 0) ? wq : (seg == 1) ? wk : (seg == 2) ? wv : wo;
    float4 v = ((const float4*)s)[r];
    ushort4 o = { f2bf(v.x), f2bf(v.y), f2bf(v.z), f2bf(v.w) };
    if (seg < 3) ((ushort4*)wqkv)[(size_t)seg * 147456 + r] = o;
    else         ((ushort4*)wob)[r] = o;
}

// ---------------------------------------------------------------------------
// bf16 MFMA GEMM (m97 pattern) — unchanged.
// MODE 0: A=x_bf16, W=packed Wqkv (2304x768); out -> bf16 (b,h,s,d) scatter.
// MODE 1: A=attn_out bf16, W=Wo; out -> fp32 row-major (M,768).
// ---------------------------------------------------------------------------
template<int MODE>
__global__ __launch_bounds__(256, 2) void mfma_gemm(
    const ushort* __restrict__ A, const ushort* __restrict__ W,
    const float* __restrict__ b0, const float* __restrict__ b1, const float* __restrict__ b2,
    ushort* __restrict__ q_o, ushort* __restrict__ k_o, ushort* __restrict__ v_o,
    float* __restrict__ f_o, int M)
{
    __shared__ __align__(16) ushort As[128 * 32];
    __shared__ __align__(16) ushort Bs[128 * 32];

    const int tid  = threadIdx.x;
    const int w    = tid >> 6, lane = tid & 63;
    const int wr   = w >> 1,  wc   = w & 1;
    const int m0   = blockIdx.x * 128;
    const int n0   = blockIdx.y * 128;
    const int srow = tid >> 2;
    const int skb  = (tid & 3) * 8;

    f32x4 acc[4][4];
#pragma unroll
    for (int m = 0; m < 4; m++)
#pragma unroll
        for (int n = 0; n < 4; n++) acc[m][n] = (f32x4)0.f;

    int ra0 = m0 + srow;       if (ra0 >= M) ra0 = M - 1;
    int ra1 = m0 + 64 + srow;  if (ra1 >= M) ra1 = M - 1;
    const int rb0 = n0 + srow, rb1 = n0 + 64 + srow;

    for (int k0 = 0; k0 < EMB; k0 += 32) {
        gl_lds16(A + (size_t)ra0 * EMB + k0 + skb, As + (w * 512));
        gl_lds16(A + (size_t)ra1 * EMB + k0 + skb, As + (2048 + w * 512));
        gl_lds16(W + (size_t)rb0 * EMB + k0 + skb, Bs + (w * 512));
        gl_lds16(W + (size_t)rb1 * EMB + k0 + skb, Bs + (2048 + w * 512));
        __syncthreads();

        bf16x8 af[4], bfr[4];
#pragma unroll
        for (int m = 0; m < 4; m++)
            af[m] = *(const bf16x8*)&As[(wr * 64 + m * 16 + (lane & 15)) * 32 + (lane >> 4) * 8];
#pragma unroll
        for (int n = 0; n < 4; n++)
            bfr[n] = *(const bf16x8*)&Bs[(wc * 64 + n * 16 + (lane & 15)) * 32 + (lane >> 4) * 8];
#pragma unroll
        for (int m = 0; m < 4; m++)
#pragma unroll
            for (int n = 0; n < 4; n++)
                acc[m][n] = __builtin_amdgcn_mfma_f32_16x16x32_bf16(af[m], bfr[n], acc[m][n], 0, 0, 0);
        __syncthreads();
    }

    const int nr = (MODE == 0) ? (n0 % EMB) : n0;
    const int mat = (MODE == 0) ? (n0 / EMB) : 0;
    const float* bias = (mat == 0) ? b0 : (mat == 1) ? b1 : b2;
    ushort* dst = (mat == 0) ? q_o : (mat == 1) ? k_o : v_o;

#pragma unroll
    for (int m = 0; m < 4; m++) {
#pragma unroll
        for (int r = 0; r < 4; r++) {
            const int gm = m0 + wr * 64 + m * 16 + (lane >> 4) * 4 + r;
            if (gm >= M) continue;
            const int bb = gm / SEQ, ss = gm - bb * SEQ;
#pragma unroll
            for (int n = 0; n < 4; n++) {
                const int col = nr + wc * 64 + n * 16 + (lane & 15);
                const float v = acc[m][n][r] + bias[col];
                if (MODE == 0) {
                    dst[(((size_t)bb * NH + (col >> 6)) * SEQ + ss) * HD + (col & 63)] = f2bf(v);
                } else {
                    f_o[(size_t)gm * EMB + col] = v;
                }
            }
        }
    }
}

// ---------------------------------------------------------------------------
// Fused attention — 8 waves/block. amdgpu_waves_per_eu(2,2) pins the
// occupancy target to 2 waves/EU (= what LDS allows anyway) -> 256-VGPR
// budget -> no scratch spills. (Rounds 2-4: backend heuristic targeted 4
// waves/EU -> 128 VGPR -> ~4 GB/dispatch of spill traffic to HBM.)
// K staged fp32 pre-scaled by 0.125 (xor-swizzled), V bf16 linear,
// rx/ry fp32 pre-scaled. LDS 152.5 KB -> 1 block/CU, 8 waves.
// ---------------------------------------------------------------------------
__global__ __launch_bounds__(512) __attribute__((amdgpu_waves_per_eu(2, 2)))
void attn_k(
    const ushort* __restrict__ xq, const ushort* __restrict__ xk, const ushort* __restrict__ xv,
    const float* __restrict__ q_tab_x, const float* __restrict__ q_tab_y,
    const float* __restrict__ v_tab_x, const float* __restrict__ v_tab_y,
    const int* __restrict__ x_dist, const int* __restrict__ y_dist,
    ushort* __restrict__ ao)
{
    __shared__ __align__(16) float  K_s[SEQ * HD];    // 50432 B fp32, chunk^=(k&7)
    __shared__ __align__(16) ushort V_s[SEQ * HD];    // 25216 B bf16 linear
    __shared__ float rx_s[SEQ * NE];                  // 22064 B
    __shared__ float ry_s[SEQ * NE];                  // 22064 B
    __shared__ float p_s[8][4][200];                  // 25600 B
    __shared__ float h_s[8][4][56];                   // 7168 B   -> 152544 total

    const int bh = blockIdx.x;
    const int b  = bh / NH;
    const int h  = bh % NH;
    const size_t base = (size_t)bh * SEQ * HD;
    const int tid = threadIdx.x;
    const int w = tid >> 6, lane = tid & 63;

    // ---- stage K (bf16 -> fp32 * 0.125, swizzled) and V (bf16 linear) ----
    for (int idx = tid; idx < SEQ * 8; idx += 512) {
        const int k = idx >> 3, c = idx & 7;
        uint4 raw = *(const uint4*)(xk + base + k * HD + c * 8);
        float f[8]; unpk8(raw, f);
        const int c0 = (2 * c) ^ (k & 7), c1 = (2 * c + 1) ^ (k & 7);
        *(float4*)&K_s[k * HD + c0 * 4] =
            make_float4(f[0] * 0.125f, f[1] * 0.125f, f[2] * 0.125f, f[3] * 0.125f);
        *(float4*)&K_s[k * HD + c1 * 4] =
            make_float4(f[4] * 0.125f, f[5] * 0.125f, f[6] * 0.125f, f[7] * 0.125f);
        uint4 vv = *(const uint4*)(xv + base + k * HD + c * 8);
        *(uint4*)&V_s[k * HD + c * 8] = vv;
    }
    // ---- rx/ry (pre-scaled by 0.125): r[q][e] = 0.125*sum_{d<32} xq[q,d]*tab[e,d]
    for (int o = tid; o < SEQ * 2 * NE; o += 512) {
        const int q = o / (2 * NE);
        const int j = o - q * (2 * NE);
        const int isx = (j < NE);
        const int e = isx ? j : (j - NE);
        const ushort* qrow = xq + base + q * HD + (isx ? 0 : 32);
        const float*  tab  = (isx ? q_tab_x : q_tab_y) + e * 32;
        float acc = 0.f;
#pragma unroll
        for (int d = 0; d < 32; d += 8) {
            float qf[8]; unpk8(*(const uint4*)(qrow + d), qf);
            float4 t0 = *(const float4*)(tab + d);
            float4 t1 = *(const float4*)(tab + d + 4);
            acc += qf[0]*t0.x + qf[1]*t0.y + qf[2]*t0.z + qf[3]*t0.w
                 + qf[4]*t1.x + qf[5]*t1.y + qf[6]*t1.z + qf[7]*t1.w;
        }
        (isx ? rx_s : ry_s)[q * NE + e] = acc * 0.125f;
    }
    __syncthreads();

    const int k0 = lane, k1 = lane + 64, k2 = lane + 128, k3 = lane + 192;
    const bool vld3 = (k3 < SEQ);
    const int k3c = vld3 ? k3 : 0;
    const int swz = lane & 7;

    for (int q0 = w * 4; q0 < SEQ; q0 += 32) {
        // ---------------- QK^T for 4 query rows ----------------
        float acc[4][4];
#pragma unroll
        for (int qq = 0; qq < 4; qq++)
#pragma unroll
            for (int s = 0; s < 4; s++) acc[qq][s] = 0.f;

        const ushort* qps[4];
#pragma unroll
        for (int qq = 0; qq < 4; qq++) {
            int qi = q0 + qq; if (qi > SEQ - 1) qi = SEQ - 1;
            qps[qq] = xq + base + qi * HD;
        }
#pragma unroll
        for (int db = 0; db < 8; db++) {
            const int p0c = (2 * db) ^ swz, p1c = (2 * db + 1) ^ swz;
            float4 kva[4], kvb[4];
            kva[0] = *(const float4*)&K_s[k0  * HD + p0c * 4];
            kvb[0] = *(const float4*)&K_s[k0  * HD + p1c * 4];
            kva[1] = *(const float4*)&K_s[k1  * HD + p0c * 4];
            kvb[1] = *(const float4*)&K_s[k1  * HD + p1c * 4];
            kva[2] = *(const float4*)&K_s[k2  * HD + p0c * 4];
            kvb[2] = *(const float4*)&K_s[k2  * HD + p1c * 4];
            kva[3] = *(const float4*)&K_s[k3c * HD + p0c * 4];
            kvb[3] = *(const float4*)&K_s[k3c * HD + p1c * 4];
#pragma unroll
            for (int qq = 0; qq < 4; qq++) {
                float qf[8]; unpk8(*(const uint4*)(qps[qq] + db * 8), qf);
#pragma unroll
                for (int s = 0; s < 4; s++) {
                    acc[qq][s] = fmaf(qf[0], kva[s].x, acc[qq][s]);
                    acc[qq][s] = fmaf(qf[1], kva[s].y, acc[qq][s]);
                    acc[qq][s] = fmaf(qf[2], kva[s].z, acc[qq][s]);
                    acc[qq][s] = fmaf(qf[3], kva[s].w, acc[qq][s]);
                    acc[qq][s] = fmaf(qf[4], kvb[s].x, acc[qq][s]);
                    acc[qq][s] = fmaf(qf[5], kvb[s].y, acc[qq][s]);
                    acc[qq][s] = fmaf(qf[6], kvb[s].z, acc[qq][s]);
                    acc[qq][s] = fmaf(qf[7], kvb[s].w, acc[qq][s]);
                }
            }
        }

        // ---------------- softmax + histogram ----------------
#pragma unroll
        for (int qq = 0; qq < 4; qq++) {
            const int q = q0 + qq;
            if (q < SEQ) {
                const int* xd = x_dist + q * SEQ;
                const int* yd = y_dist + q * SEQ;
                const int e0x = xd[k0], e1x = xd[k1], e2x = xd[k2], e3x = xd[k3c];
                const int e0y = yd[k0], e1y = yd[k1], e2y = yd[k2], e3y = yd[k3c];
                const float* rx = rx_s + q * NE;
                const float* ry = ry_s + q * NE;
                const float l0 = acc[qq][0] + rx[e0x] + ry[e0y];
                const float l1 = acc[qq][1] + rx[e1x] + ry[e1y];
                const float l2 = acc[qq][2] + rx[e2x] + ry[e2y];
                const float l3 = vld3 ? (acc[qq][3] + rx[e3x] + ry[e3y]) : -1e30f;
                float mx = fmaxf(fmaxf(l0, l1), fmaxf(l2, l3));
#pragma unroll
                for (int off = 32; off >= 1; off >>= 1) mx = fmaxf(mx, __shfl_xor(mx, off));
                float p0 = __expf(l0 - mx), p1 = __expf(l1 - mx), p2 = __expf(l2 - mx);
                float p3 = vld3 ? __expf(l3 - mx) : 0.f;
                float sm = p0 + p1 + p2 + p3;
#pragma unroll
                for (int off = 32; off >= 1; off >>= 1) sm += __shfl_xor(sm, off);
                const float inv = 1.f / sm;
                p0 *= inv; p1 *= inv; p2 *= inv; p3 *= inv;

                if (lane < 2 * NE) h_s[w][qq][lane] = 0.f;
                p_s[w][qq][k0] = p0;
                p_s[w][qq][k1] = p1;
                p_s[w][qq][k2] = p2;
                if (vld3) p_s[w][qq][k3] = p3;
                atomicAdd(&h_s[w][qq][e0x], p0);
                atomicAdd(&h_s[w][qq][NE + e0y], p0);
                atomicAdd(&h_s[w][qq][e1x], p1);
                atomicAdd(&h_s[w][qq][NE + e1y], p1);
                atomicAdd(&h_s[w][qq][e2x], p2);
                atomicAdd(&h_s[w][qq][NE + e2y], p2);
                if (vld3) {
                    atomicAdd(&h_s[w][qq][e3x], p3);
                    atomicAdd(&h_s[w][qq][NE + e3y], p3);
                }
            }
        }

        // ---------------- PV (V bf16 from LDS) + v_pos ----------------
        const int d4 = (lane & 15) * 4;
        const int kk = lane >> 4;
        float4 o4[4];
#pragma unroll
        for (int qq = 0; qq < 4; qq++) o4[qq] = make_float4(0.f, 0.f, 0.f, 0.f);

        for (int kb = 0; kb < SEQ; kb += 4) {
            const int k = kb + kk;
            const bool ok = (k < SEQ);
            const int kc = ok ? k : 0;
            uint2 vv = *(const uint2*)&V_s[kc * HD + d4];
            const float vf0 = bfl(vv.x), vf1 = bfh(vv.x), vf2 = bfl(vv.y), vf3 = bfh(vv.y);
#pragma unroll
            for (int qq = 0; qq < 4; qq++) {
                const float p = ok ? p_s[w][qq][k] : 0.f;
                o4[qq].x = fmaf(p, vf0, o4[qq].x);
                o4[qq].y = fmaf(p, vf1, o4[qq].y);
                o4[qq].z = fmaf(p, vf2, o4[qq].z);
                o4[qq].w = fmaf(p, vf3, o4[qq].w);
            }
        }
#pragma unroll
        for (int qq = 0; qq < 4; qq++) {
            o4[qq].x += __shfl_xor(o4[qq].x, 16); o4[qq].x += __shfl_xor(o4[qq].x, 32);
            o4[qq].y += __shfl_xor(o4[qq].y, 16); o4[qq].y += __shfl_xor(o4[qq].y, 32);
            o4[qq].z += __shfl_xor(o4[qq].z, 16); o4[qq].z += __shfl_xor(o4[qq].z, 32);
            o4[qq].w += __shfl_xor(o4[qq].w, 16); o4[qq].w += __shfl_xor(o4[qq].w, 32);
        }

        if (kk == 0) {
            const bool isx = (d4 < 32);
            const int dl = d4 & 31;
            const float* tab = (isx ? v_tab_x : v_tab_y) + dl;
#pragma unroll
            for (int e = 0; e < NE; e++) {
                float4 tv = *(const float4*)(tab + e * 32);
#pragma unroll
                for (int qq = 0; qq < 4; qq++) {
                    const float hh = h_s[w][qq][(isx ? 0 : NE) + e];
                    o4[qq].x = fmaf(hh, tv.x, o4[qq].x);
                    o4[qq].y = fmaf(hh, tv.y, o4[qq].y);
                    o4[qq].z = fmaf(hh, tv.z, o4[qq].z);
                    o4[qq].w = fmaf(hh, tv.w, o4[qq].w);
                }
            }
#pragma unroll
            for (int qq = 0; qq < 4; qq++) {
                const int q = q0 + qq;
                if (q < SEQ) {
                    unsigned r0 = ((unsigned)f2bf(o4[qq].y) << 16) | f2bf(o4[qq].x);
                    unsigned r1 = ((unsigned)f2bf(o4[qq].w) << 16) | f2bf(o4[qq].z);
                    uint2 pk = { r0, r1 };
                    *(uint2*)(ao + ((size_t)(b * SEQ + q) * EMB) + h * HD + d4) = pk;
                }
            }
        }
    }
}

extern "C" void kernel_launch(void* const* d_in, const int* in_sizes, int n_in,
                              void* d_out, int out_size, void* d_ws, size_t ws_size,
                              hipStream_t stream) {
    const float* x       = (const float*)d_in[0];
    const float* Wq      = (const float*)d_in[1];
    const float* bq      = (const float*)d_in[2];
    const float* Wk      = (const float*)d_in[3];
    const float* bk      = (const float*)d_in[4];
    const float* Wv      = (const float*)d_in[5];
    const float* bv      = (const float*)d_in[6];
    const float* Wo      = (const float*)d_in[7];
    const float* bo      = (const float*)d_in[8];
    const float* q_tab_x = (const float*)d_in[9];
    const float* q_tab_y = (const float*)d_in[10];
    const float* v_tab_x = (const float*)d_in[11];
    const float* v_tab_y = (const float*)d_in[12];
    const int*   x_dist  = (const int*)d_in[13];
    const int*   y_dist  = (const int*)d_in[14];
    float* out = (float*)d_out;

    const int M  = in_sizes[0] / EMB;   // 12608
    const int Bc = M / SEQ;             // 64

    ushort* xb   = (ushort*)d_ws;                       // M*768
    ushort* wqkv = xb   + (size_t)M * EMB;              // 2304*768
    ushort* wob  = wqkv + (size_t)3 * EMB * EMB;        // 768*768
    ushort* xqb  = wob  + (size_t)EMB * EMB;            // (b,h,s,d) bf16
    ushort* xkb  = xqb  + (size_t)M * EMB;
    ushort* xvb  = xkb  + (size_t)M * EMB;
    ushort* aob  = xvb  + (size_t)M * EMB;              // (b,s,h*d) bf16

    const int n4x = M * EMB / 4;
    cvt_k<<<dim3((n4x + 255) / 256), dim3(256), 0, stream>>>(x, xb, n4x);
    cvt_w4<<<dim3(2304), dim3(256), 0, stream>>>(Wq, Wk, Wv, Wo, wqkv, wob);

    mfma_gemm<0><<<dim3((M + 127) / 128, 18), dim3(256), 0, stream>>>(
        xb, wqkv, bq, bk, bv, xqb, xkb, xvb, nullptr, M);

    attn_k<<<dim3(Bc * NH), dim3(512), 0, stream>>>(xqb, xkb, xvb, q_tab_x, q_tab_y,
                                                    v_tab_x, v_tab_y, x_dist, y_dist, aob);

    mfma_gemm<1><<<dim3((M + 127) / 128, 6), dim3(256), 0, stream>>>(
        aob, wob, bo, bo, bo, nullptr, nullptr, nullptr, out, M);
}

// Round 6
// 1820.705 us; speedup vs baseline: 1.0083x; 1.0083x over previous
//
#include <hip/hip_runtime.h>
#include <math.h>

#define SEQ 197
#define EMB 768
#define NH  12
#define HD  64
#define NE  28

typedef __attribute__((ext_vector_type(8))) __bf16 bf16x8;
typedef __attribute__((ext_vector_type(4))) float  f32x4;
typedef __attribute__((ext_vector_type(8))) float  f32x8;

__device__ __forceinline__ unsigned short f2bf(float f) {
    unsigned u = __float_as_uint(f);
    u += 0x7fffu + ((u >> 16) & 1u);
    return (unsigned short)(u >> 16);
}
__device__ __forceinline__ float bfl(unsigned u) { return __uint_as_float(u << 16); }
__device__ __forceinline__ float bfh(unsigned u) { return __uint_as_float(u & 0xffff0000u); }

// by-VALUE unpack: no address-taken local array -> stays in VGPRs.
// (rounds 2-5 used unpk8(uint4, float* f): the float f[8] locals were
//  address-taken, SROA left them in scratch -> 3.2GB/815MB per-dispatch
//  spill traffic, VGPR_Count collapsed to 128.)
__device__ __forceinline__ f32x8 unpk8v(uint4 v) {
    f32x8 r;
    r[0] = bfl(v.x); r[1] = bfh(v.x); r[2] = bfl(v.y); r[3] = bfh(v.y);
    r[4] = bfl(v.z); r[5] = bfh(v.z); r[6] = bfl(v.w); r[7] = bfh(v.w);
    return r;
}

__device__ __forceinline__ void gl_lds16(const ushort* g, ushort* l) {
    __builtin_amdgcn_global_load_lds(
        (const __attribute__((address_space(1))) unsigned int*)g,
        (__attribute__((address_space(3))) unsigned int*)l, 16, 0, 0);
}

// ---------------------------------------------------------------------------
// fp32 -> bf16 converters
// ---------------------------------------------------------------------------
__global__ void cvt_k(const float* __restrict__ src, ushort* __restrict__ dst, int n4) {
    int i = blockIdx.x * 256 + threadIdx.x;
    if (i < n4) {
        float4 v = ((const float4*)src)[i];
        ushort4 o = { f2bf(v.x), f2bf(v.y), f2bf(v.z), f2bf(v.w) };
        ((ushort4*)dst)[i] = o;
    }
}

__global__ void cvt_w4(const float* __restrict__ wq, const float* __restrict__ wk,
                       const float* __restrict__ wv, const float* __restrict__ wo,
                       ushort* __restrict__ wqkv, ushort* __restrict__ wob) {
    int i = blockIdx.x * 256 + threadIdx.x;          // 4 * 147456 total
    if (i >= 4 * 147456) return;
    int seg = i / 147456, r = i - seg * 147456;
    const float* s = (seg == 0) ? wq : (seg == 1) ? wk : (seg == 2) ? wv : wo;
    float4 v = ((const float4*)s)[r];
    ushort4 o = { f2bf(v.x), f2bf(v.y), f2bf(v.z), f2bf(v.w) };
    if (seg < 3) ((ushort4*)wqkv)[(size_t)seg * 147456 + r] = o;
    else         ((ushort4*)wob)[r] = o;
}

// ---------------------------------------------------------------------------
// bf16 MFMA GEMM (m97 pattern) — unchanged.
// MODE 0: A=x_bf16, W=packed Wqkv (2304x768); out -> bf16 (b,h,s,d) scatter.
// MODE 1: A=attn_out bf16, W=Wo; out -> fp32 row-major (M,768).
// ---------------------------------------------------------------------------
template<int MODE>
__global__ __launch_bounds__(256, 2) void mfma_gemm(
    const ushort* __restrict__ A, const ushort* __restrict__ W,
    const float* __restrict__ b0, const float* __restrict__ b1, const float* __restrict__ b2,
    ushort* __restrict__ q_o, ushort* __restrict__ k_o, ushort* __restrict__ v_o,
    float* __restrict__ f_o, int M)
{
    __shared__ __align__(16) ushort As[128 * 32];
    __shared__ __align__(16) ushort Bs[128 * 32];

    const int tid  = threadIdx.x;
    const int w    = tid >> 6, lane = tid & 63;
    const int wr   = w >> 1,  wc   = w & 1;
    const int m0   = blockIdx.x * 128;
    const int n0   = blockIdx.y * 128;
    const int srow = tid >> 2;
    const int skb  = (tid & 3) * 8;

    f32x4 acc[4][4];
#pragma unroll
    for (int m = 0; m < 4; m++)
#pragma unroll
        for (int n = 0; n < 4; n++) acc[m][n] = (f32x4)0.f;

    int ra0 = m0 + srow;       if (ra0 >= M) ra0 = M - 1;
    int ra1 = m0 + 64 + srow;  if (ra1 >= M) ra1 = M - 1;
    const int rb0 = n0 + srow, rb1 = n0 + 64 + srow;

    for (int k0 = 0; k0 < EMB; k0 += 32) {
        gl_lds16(A + (size_t)ra0 * EMB + k0 + skb, As + (w * 512));
        gl_lds16(A + (size_t)ra1 * EMB + k0 + skb, As + (2048 + w * 512));
        gl_lds16(W + (size_t)rb0 * EMB + k0 + skb, Bs + (w * 512));
        gl_lds16(W + (size_t)rb1 * EMB + k0 + skb, Bs + (2048 + w * 512));
        __syncthreads();

        bf16x8 af[4], bfr[4];
#pragma unroll
        for (int m = 0; m < 4; m++)
            af[m] = *(const bf16x8*)&As[(wr * 64 + m * 16 + (lane & 15)) * 32 + (lane >> 4) * 8];
#pragma unroll
        for (int n = 0; n < 4; n++)
            bfr[n] = *(const bf16x8*)&Bs[(wc * 64 + n * 16 + (lane & 15)) * 32 + (lane >> 4) * 8];
#pragma unroll
        for (int m = 0; m < 4; m++)
#pragma unroll
            for (int n = 0; n < 4; n++)
                acc[m][n] = __builtin_amdgcn_mfma_f32_16x16x32_bf16(af[m], bfr[n], acc[m][n], 0, 0, 0);
        __syncthreads();
    }

    const int nr = (MODE == 0) ? (n0 % EMB) : n0;
    const int mat = (MODE == 0) ? (n0 / EMB) : 0;
    const float* bias = (mat == 0) ? b0 : (mat == 1) ? b1 : b2;
    ushort* dst = (mat == 0) ? q_o : (mat == 1) ? k_o : v_o;

#pragma unroll
    for (int m = 0; m < 4; m++) {
#pragma unroll
        for (int r = 0; r < 4; r++) {
            const int gm = m0 + wr * 64 + m * 16 + (lane >> 4) * 4 + r;
            if (gm >= M) continue;
            const int bb = gm / SEQ, ss = gm - bb * SEQ;
#pragma unroll
            for (int n = 0; n < 4; n++) {
                const int col = nr + wc * 64 + n * 16 + (lane & 15);
                const float v = acc[m][n][r] + bias[col];
                if (MODE == 0) {
                    dst[(((size_t)bb * NH + (col >> 6)) * SEQ + ss) * HD + (col & 63)] = f2bf(v);
                } else {
                    f_o[(size_t)gm * EMB + col] = v;
                }
            }
        }
    }
}

// ---------------------------------------------------------------------------
// Fused attention — 8 waves/block, 512 thr, 152.5 KB LDS (1 block/CU).
// All bf16 unpacking is by-VALUE f32x8 (no address-taken local arrays).
// K staged fp32 pre-scaled 0.125 (xor-swizzled), V bf16 linear, rx/ry fp32.
// ---------------------------------------------------------------------------
__global__ __launch_bounds__(512) __attribute__((amdgpu_waves_per_eu(2, 2)))
void attn_k(
    const ushort* __restrict__ xq, const ushort* __restrict__ xk, const ushort* __restrict__ xv,
    const float* __restrict__ q_tab_x, const float* __restrict__ q_tab_y,
    const float* __restrict__ v_tab_x, const float* __restrict__ v_tab_y,
    const int* __restrict__ x_dist, const int* __restrict__ y_dist,
    ushort* __restrict__ ao)
{
    __shared__ __align__(16) float  K_s[SEQ * HD];    // 50432 B fp32, chunk^=(k&7)
    __shared__ __align__(16) ushort V_s[SEQ * HD];    // 25216 B bf16 linear
    __shared__ float rx_s[SEQ * NE];                  // 22064 B
    __shared__ float ry_s[SEQ * NE];                  // 22064 B
    __shared__ float p_s[8][4][200];                  // 25600 B
    __shared__ float h_s[8][4][56];                   // 7168 B   -> 152544 total

    const int bh = blockIdx.x;
    const int b  = bh / NH;
    const int h  = bh % NH;
    const size_t base = (size_t)bh * SEQ * HD;
    const int tid = threadIdx.x;
    const int w = tid >> 6, lane = tid & 63;

    // ---- stage K (bf16 -> fp32 * 0.125, swizzled) and V (bf16 linear) ----
    for (int idx = tid; idx < SEQ * 8; idx += 512) {
        const int k = idx >> 3, c = idx & 7;
        uint4 raw = *(const uint4*)(xk + base + k * HD + c * 8);
        f32x8 f = unpk8v(raw);
        const int c0 = (2 * c) ^ (k & 7), c1 = (2 * c + 1) ^ (k & 7);
        *(float4*)&K_s[k * HD + c0 * 4] =
            make_float4(f[0] * 0.125f, f[1] * 0.125f, f[2] * 0.125f, f[3] * 0.125f);
        *(float4*)&K_s[k * HD + c1 * 4] =
            make_float4(f[4] * 0.125f, f[5] * 0.125f, f[6] * 0.125f, f[7] * 0.125f);
        uint4 vv = *(const uint4*)(xv + base + k * HD + c * 8);
        *(uint4*)&V_s[k * HD + c * 8] = vv;
    }
    // ---- rx/ry (pre-scaled by 0.125): r[q][e] = 0.125*sum_{d<32} xq[q,d]*tab[e,d]
    for (int o = tid; o < SEQ * 2 * NE; o += 512) {
        const int q = o / (2 * NE);
        const int j = o - q * (2 * NE);
        const int isx = (j < NE);
        const int e = isx ? j : (j - NE);
        const ushort* qrow = xq + base + q * HD + (isx ? 0 : 32);
        const float*  tab  = (isx ? q_tab_x : q_tab_y) + e * 32;
        float acc = 0.f;
#pragma unroll
        for (int d = 0; d < 32; d += 8) {
            f32x8 qf = unpk8v(*(const uint4*)(qrow + d));
            float4 t0 = *(const float4*)(tab + d);
            float4 t1 = *(const float4*)(tab + d + 4);
            acc += qf[0]*t0.x + qf[1]*t0.y + qf[2]*t0.z + qf[3]*t0.w
                 + qf[4]*t1.x + qf[5]*t1.y + qf[6]*t1.z + qf[7]*t1.w;
        }
        (isx ? rx_s : ry_s)[q * NE + e] = acc * 0.125f;
    }
    __syncthreads();

    const int k0 = lane, k1 = lane + 64, k2 = lane + 128, k3 = lane + 192;
    const bool vld3 = (k3 < SEQ);
    const int k3c = vld3 ? k3 : 0;
    const int swz = lane & 7;

    for (int q0 = w * 4; q0 < SEQ; q0 += 32) {
        // ---------------- QK^T for 4 query rows ----------------
        float acc[4][4];
#pragma unroll
        for (int qq = 0; qq < 4; qq++)
#pragma unroll
            for (int s = 0; s < 4; s++) acc[qq][s] = 0.f;

        const ushort* qps[4];
#pragma unroll
        for (int qq = 0; qq < 4; qq++) {
            int qi = q0 + qq; if (qi > SEQ - 1) qi = SEQ - 1;
            qps[qq] = xq + base + qi * HD;
        }
#pragma unroll
        for (int db = 0; db < 8; db++) {
            const int p0c = (2 * db) ^ swz, p1c = (2 * db + 1) ^ swz;
            float4 kva[4], kvb[4];
            kva[0] = *(const float4*)&K_s[k0  * HD + p0c * 4];
            kvb[0] = *(const float4*)&K_s[k0  * HD + p1c * 4];
            kva[1] = *(const float4*)&K_s[k1  * HD + p0c * 4];
            kvb[1] = *(const float4*)&K_s[k1  * HD + p1c * 4];
            kva[2] = *(const float4*)&K_s[k2  * HD + p0c * 4];
            kvb[2] = *(const float4*)&K_s[k2  * HD + p1c * 4];
            kva[3] = *(const float4*)&K_s[k3c * HD + p0c * 4];
            kvb[3] = *(const float4*)&K_s[k3c * HD + p1c * 4];
#pragma unroll
            for (int qq = 0; qq < 4; qq++) {
                f32x8 qf = unpk8v(*(const uint4*)(qps[qq] + db * 8));
#pragma unroll
                for (int s = 0; s < 4; s++) {
                    acc[qq][s] = fmaf(qf[0], kva[s].x, acc[qq][s]);
                    acc[qq][s] = fmaf(qf[1], kva[s].y, acc[qq][s]);
                    acc[qq][s] = fmaf(qf[2], kva[s].z, acc[qq][s]);
                    acc[qq][s] = fmaf(qf[3], kva[s].w, acc[qq][s]);
                    acc[qq][s] = fmaf(qf[4], kvb[s].x, acc[qq][s]);
                    acc[qq][s] = fmaf(qf[5], kvb[s].y, acc[qq][s]);
                    acc[qq][s] = fmaf(qf[6], kvb[s].z, acc[qq][s]);
                    acc[qq][s] = fmaf(qf[7], kvb[s].w, acc[qq][s]);
                }
            }
        }

        // ---------------- softmax + histogram ----------------
#pragma unroll
        for (int qq = 0; qq < 4; qq++) {
            const int q = q0 + qq;
            if (q < SEQ) {
                const int* xd = x_dist + q * SEQ;
                const int* yd = y_dist + q * SEQ;
                const int e0x = xd[k0], e1x = xd[k1], e2x = xd[k2], e3x = xd[k3c];
                const int e0y = yd[k0], e1y = yd[k1], e2y = yd[k2], e3y = yd[k3c];
                const float* rx = rx_s + q * NE;
                const float* ry = ry_s + q * NE;
                const float l0 = acc[qq][0] + rx[e0x] + ry[e0y];
                const float l1 = acc[qq][1] + rx[e1x] + ry[e1y];
                const float l2 = acc[qq][2] + rx[e2x] + ry[e2y];
                const float l3 = vld3 ? (acc[qq][3] + rx[e3x] + ry[e3y]) : -1e30f;
                float mx = fmaxf(fmaxf(l0, l1), fmaxf(l2, l3));
#pragma unroll
                for (int off = 32; off >= 1; off >>= 1) mx = fmaxf(mx, __shfl_xor(mx, off));
                float p0 = __expf(l0 - mx), p1 = __expf(l1 - mx), p2 = __expf(l2 - mx);
                float p3 = vld3 ? __expf(l3 - mx) : 0.f;
                float sm = p0 + p1 + p2 + p3;
#pragma unroll
                for (int off = 32; off >= 1; off >>= 1) sm += __shfl_xor(sm, off);
                const float inv = 1.f / sm;
                p0 *= inv; p1 *= inv; p2 *= inv; p3 *= inv;

                if (lane < 2 * NE) h_s[w][qq][lane] = 0.f;
                p_s[w][qq][k0] = p0;
                p_s[w][qq][k1] = p1;
                p_s[w][qq][k2] = p2;
                if (vld3) p_s[w][qq][k3] = p3;
                atomicAdd(&h_s[w][qq][e0x], p0);
                atomicAdd(&h_s[w][qq][NE + e0y], p0);
                atomicAdd(&h_s[w][qq][e1x], p1);
                atomicAdd(&h_s[w][qq][NE + e1y], p1);
                atomicAdd(&h_s[w][qq][e2x], p2);
                atomicAdd(&h_s[w][qq][NE + e2y], p2);
                if (vld3) {
                    atomicAdd(&h_s[w][qq][e3x], p3);
                    atomicAdd(&h_s[w][qq][NE + e3y], p3);
                }
            }
        }

        // ---------------- PV (V bf16 from LDS) + v_pos ----------------
        const int d4 = (lane & 15) * 4;
        const int kk = lane >> 4;
        float4 o4[4];
#pragma unroll
        for (int qq = 0; qq < 4; qq++) o4[qq] = make_float4(0.f, 0.f, 0.f, 0.f);

        for (int kb = 0; kb < SEQ; kb += 4) {
            const int k = kb + kk;
            const bool ok = (k < SEQ);
            const int kc = ok ? k : 0;
            uint2 vv = *(const uint2*)&V_s[kc * HD + d4];
            const float vf0 = bfl(vv.x), vf1 = bfh(vv.x), vf2 = bfl(vv.y), vf3 = bfh(vv.y);
#pragma unroll
            for (int qq = 0; qq < 4; qq++) {
                const float p = ok ? p_s[w][qq][k] : 0.f;
                o4[qq].x = fmaf(p, vf0, o4[qq].x);
                o4[qq].y = fmaf(p, vf1, o4[qq].y);
                o4[qq].z = fmaf(p, vf2, o4[qq].z);
                o4[qq].w = fmaf(p, vf3, o4[qq].w);
            }
        }
#pragma unroll
        for (int qq = 0; qq < 4; qq++) {
            o4[qq].x += __shfl_xor(o4[qq].x, 16); o4[qq].x += __shfl_xor(o4[qq].x, 32);
            o4[qq].y += __shfl_xor(o4[qq].y, 16); o4[qq].y += __shfl_xor(o4[qq].y, 32);
            o4[qq].z += __shfl_xor(o4[qq].z, 16); o4[qq].z += __shfl_xor(o4[qq].z, 32);
            o4[qq].w += __shfl_xor(o4[qq].w, 16); o4[qq].w += __shfl_xor(o4[qq].w, 32);
        }

        if (kk == 0) {
            const bool isx = (d4 < 32);
            const int dl = d4 & 31;
            const float* tab = (isx ? v_tab_x : v_tab_y) + dl;
#pragma unroll
            for (int e = 0; e < NE; e++) {
                float4 tv = *(const float4*)(tab + e * 32);
#pragma unroll
                for (int qq = 0; qq < 4; qq++) {
                    const float hh = h_s[w][qq][(isx ? 0 : NE) + e];
                    o4[qq].x = fmaf(hh, tv.x, o4[qq].x);
                    o4[qq].y = fmaf(hh, tv.y, o4[qq].y);
                    o4[qq].z = fmaf(hh, tv.z, o4[qq].z);
                    o4[qq].w = fmaf(hh, tv.w, o4[qq].w);
                }
            }
#pragma unroll
            for (int qq = 0; qq < 4; qq++) {
                const int q = q0 + qq;
                if (q < SEQ) {
                    unsigned r0 = ((unsigned)f2bf(o4[qq].y) << 16) | f2bf(o4[qq].x);
                    unsigned r1 = ((unsigned)f2bf(o4[qq].w) << 16) | f2bf(o4[qq].z);
                    uint2 pk = { r0, r1 };
                    *(uint2*)(ao + ((size_t)(b * SEQ + q) * EMB) + h * HD + d4) = pk;
                }
            }
        }
    }
}

extern "C" void kernel_launch(void* const* d_in, const int* in_sizes, int n_in,
                              void* d_out, int out_size, void* d_ws, size_t ws_size,
                              hipStream_t stream) {
    const float* x       = (const float*)d_in[0];
    const float* Wq      = (const float*)d_in[1];
    const float* bq      = (const float*)d_in[2];
    const float* Wk      = (const float*)d_in[3];
    const float* bk      = (const float*)d_in[4];
    const float* Wv      = (const float*)d_in[5];
    const float* bv      = (const float*)d_in[6];
    const float* Wo      = (const float*)d_in[7];
    const float* bo      = (const float*)d_in[8];
    const float* q_tab_x = (const float*)d_in[9];
    const float* q_tab_y = (const float*)d_in[10];
    const float* v_tab_x = (const float*)d_in[11];
    const float* v_tab_y = (const float*)d_in[12];
    const int*   x_dist  = (const int*)d_in[13];
    const int*   y_dist  = (const int*)d_in[14];
    float* out = (float*)d_out;

    const int M  = in_sizes[0] / EMB;   // 12608
    const int Bc = M / SEQ;             // 64

    ushort* xb   = (ushort*)d_ws;                       // M*768
    ushort* wqkv = xb   + (size_t)M * EMB;              // 2304*768
    ushort* wob  = wqkv + (size_t)3 * EMB * EMB;        // 768*768
    ushort* xqb  = wob  + (size_t)EMB * EMB;            // (b,h,s,d) bf16
    ushort* xkb  = xqb  + (size_t)M * EMB;
    ushort* xvb  = xkb  + (size_t)M * EMB;
    ushort* aob  = xvb  + (size_t)M * EMB;              // (b,s,h*d) bf16

    const int n4x = M * EMB / 4;
    cvt_k<<<dim3((n4x + 255) / 256), dim3(256), 0, stream>>>(x, xb, n4x);
    cvt_w4<<<dim3(2304), dim3(256), 0, stream>>>(Wq, Wk, Wv, Wo, wqkv, wob);

    mfma_gemm<0><<<dim3((M + 127) / 128, 18), dim3(256), 0, stream>>>(
        xb, wqkv, bq, bk, bv, xqb, xkb, xvb, nullptr, M);

    attn_k<<<dim3(Bc * NH), dim3(512), 0, stream>>>(xqb, xkb, xvb, q_tab_x, q_tab_y,
                                                    v_tab_x, v_tab_y, x_dist, y_dist, aob);

    mfma_gemm<1><<<dim3((M + 127) / 128, 6), dim3(256), 0, stream>>>(
        aob, wob, bo, bo, bo, nullptr, nullptr, nullptr, out, M);
}

// Round 7
// 1140.844 us; speedup vs baseline: 1.6091x; 1.5959x over previous
//
#include <hip/hip_runtime.h>
#include <math.h>

#define SEQ 197
#define EMB 768
#define NH  12
#define HD  64
#define NE  28

typedef __attribute__((ext_vector_type(8))) __bf16 bf16x8;
typedef __attribute__((ext_vector_type(4))) float  f32x4;
typedef __attribute__((ext_vector_type(8))) float  f32x8;

__device__ __forceinline__ unsigned short f2bf(float f) {
    unsigned u = __float_as_uint(f);
    u += 0x7fffu + ((u >> 16) & 1u);
    return (unsigned short)(u >> 16);
}
__device__ __forceinline__ float bfl(unsigned u) { return __uint_as_float(u << 16); }
__device__ __forceinline__ float bfh(unsigned u) { return __uint_as_float(u & 0xffff0000u); }
__device__ __forceinline__ f32x8 unpk8v(uint4 v) {
    f32x8 r;
    r[0] = bfl(v.x); r[1] = bfh(v.x); r[2] = bfl(v.y); r[3] = bfh(v.y);
    r[4] = bfl(v.z); r[5] = bfh(v.z); r[6] = bfl(v.w); r[7] = bfh(v.w);
    return r;
}

__device__ __forceinline__ void gl_lds16(const ushort* g, ushort* l) {
    __builtin_amdgcn_global_load_lds(
        (const __attribute__((address_space(1))) unsigned int*)g,
        (__attribute__((address_space(3))) unsigned int*)l, 16, 0, 0);
}

// ---------------------------------------------------------------------------
// fp32 -> bf16 converters
// ---------------------------------------------------------------------------
__global__ void cvt_k(const float* __restrict__ src, ushort* __restrict__ dst, int n4) {
    int i = blockIdx.x * 256 + threadIdx.x;
    if (i < n4) {
        float4 v = ((const float4*)src)[i];
        ushort4 o = { f2bf(v.x), f2bf(v.y), f2bf(v.z), f2bf(v.w) };
        ((ushort4*)dst)[i] = o;
    }
}

__global__ void cvt_w4(const float* __restrict__ wq, const float* __restrict__ wk,
                       const float* __restrict__ wv, const float* __restrict__ wo,
                       ushort* __restrict__ wqkv, ushort* __restrict__ wob) {
    int i = blockIdx.x * 256 + threadIdx.x;          // 4 * 147456 total
    if (i >= 4 * 147456) return;
    int seg = i / 147456, r = i - seg * 147456;
    const float* s = (seg == 0) ? wq : (seg == 1) ? wk : (seg == 2) ? wv : wo;
    float4 v = ((const float4*)s)[r];
    ushort4 o = { f2bf(v.x), f2bf(v.y), f2bf(v.z), f2bf(v.w) };
    if (seg < 3) ((ushort4*)wqkv)[(size_t)seg * 147456 + r] = o;
    else         ((ushort4*)wob)[r] = o;
}

// ---------------------------------------------------------------------------
// bf16 MFMA GEMM (m97 pattern).
// MODE 0: A=x_bf16, W=packed Wqkv; q,k -> fp32 (b,h,s,d); v -> bf16 (b,h,s,d).
// MODE 1: A=attn_out bf16, W=Wo; out -> fp32 row-major (M,768).
// ---------------------------------------------------------------------------
template<int MODE>
__global__ __launch_bounds__(256, 2) void mfma_gemm(
    const ushort* __restrict__ A, const ushort* __restrict__ W,
    const float* __restrict__ b0, const float* __restrict__ b1, const float* __restrict__ b2,
    float* __restrict__ q_o, float* __restrict__ k_o, ushort* __restrict__ v_o,
    float* __restrict__ f_o, int M)
{
    __shared__ __align__(16) ushort As[128 * 32];
    __shared__ __align__(16) ushort Bs[128 * 32];

    const int tid  = threadIdx.x;
    const int w    = tid >> 6, lane = tid & 63;
    const int wr   = w >> 1,  wc   = w & 1;
    const int m0   = blockIdx.x * 128;
    const int n0   = blockIdx.y * 128;
    const int srow = tid >> 2;
    const int skb  = (tid & 3) * 8;

    f32x4 acc[4][4];
#pragma unroll
    for (int m = 0; m < 4; m++)
#pragma unroll
        for (int n = 0; n < 4; n++) acc[m][n] = (f32x4)0.f;

    int ra0 = m0 + srow;       if (ra0 >= M) ra0 = M - 1;
    int ra1 = m0 + 64 + srow;  if (ra1 >= M) ra1 = M - 1;
    const int rb0 = n0 + srow, rb1 = n0 + 64 + srow;

    for (int k0 = 0; k0 < EMB; k0 += 32) {
        gl_lds16(A + (size_t)ra0 * EMB + k0 + skb, As + (w * 512));
        gl_lds16(A + (size_t)ra1 * EMB + k0 + skb, As + (2048 + w * 512));
        gl_lds16(W + (size_t)rb0 * EMB + k0 + skb, Bs + (w * 512));
        gl_lds16(W + (size_t)rb1 * EMB + k0 + skb, Bs + (2048 + w * 512));
        __syncthreads();

        bf16x8 af[4], bfr[4];
#pragma unroll
        for (int m = 0; m < 4; m++)
            af[m] = *(const bf16x8*)&As[(wr * 64 + m * 16 + (lane & 15)) * 32 + (lane >> 4) * 8];
#pragma unroll
        for (int n = 0; n < 4; n++)
            bfr[n] = *(const bf16x8*)&Bs[(wc * 64 + n * 16 + (lane & 15)) * 32 + (lane >> 4) * 8];
#pragma unroll
        for (int m = 0; m < 4; m++)
#pragma unroll
            for (int n = 0; n < 4; n++)
                acc[m][n] = __builtin_amdgcn_mfma_f32_16x16x32_bf16(af[m], bfr[n], acc[m][n], 0, 0, 0);
        __syncthreads();
    }

    const int nr = (MODE == 0) ? (n0 % EMB) : n0;
    const int mat = (MODE == 0) ? (n0 / EMB) : 0;
    const float* bias = (mat == 0) ? b0 : (mat == 1) ? b1 : b2;

#pragma unroll
    for (int m = 0; m < 4; m++) {
#pragma unroll
        for (int r = 0; r < 4; r++) {
            const int gm = m0 + wr * 64 + m * 16 + (lane >> 4) * 4 + r;
            if (gm >= M) continue;
            const int bb = gm / SEQ, ss = gm - bb * SEQ;
#pragma unroll
            for (int n = 0; n < 4; n++) {
                const int col = nr + wc * 64 + n * 16 + (lane & 15);
                const float v = acc[m][n][r] + bias[col];
                if (MODE == 0) {
                    const size_t oi = (((size_t)bb * NH + (col >> 6)) * SEQ + ss) * HD + (col & 63);
                    if (mat == 0)      q_o[oi] = v;
                    else if (mat == 1) k_o[oi] = v;
                    else               v_o[oi] = f2bf(v);
                } else {
                    f_o[(size_t)gm * EMB + col] = v;
                }
            }
        }
    }
}

// ---------------------------------------------------------------------------
// Fused attention — round-1 kernel verbatim (fp32 math, 256 thr, 4 waves,
// K_s/V_s fp32 in LDS, 161KB, 1 block/CU). Boundary changes only:
//   - V input arrives bf16; unpacked to fp32 V_s during staging.
//   - final store packs bf16 into ao (feeds the MFMA output projection).
// ---------------------------------------------------------------------------
__global__ __launch_bounds__(256) void attn_k(
    const float* __restrict__ xq, const float* __restrict__ xk, const ushort* __restrict__ xv,
    const float* __restrict__ q_tab_x, const float* __restrict__ q_tab_y,
    const float* __restrict__ v_tab_x, const float* __restrict__ v_tab_y,
    const int* __restrict__ x_dist, const int* __restrict__ y_dist,
    ushort* __restrict__ ao)
{
    __shared__ __align__(16) float K_s[SEQ * HD];     // swizzled rows (fp32)
    __shared__ __align__(16) float V_s[SEQ * HD];     // linear rows (fp32)
    __shared__ float rx_s[SEQ * NE];
    __shared__ float ry_s[SEQ * NE];
    __shared__ float p_s[4][4][SEQ];                  // [wave][qq][k]
    __shared__ float h_s[4][4][2 * NE];               // [wave][qq][x | y]

    const int bh = blockIdx.x;
    const int b  = bh / NH;
    const int h  = bh % NH;
    const float*  __restrict__ xq_r = xq + (size_t)bh * SEQ * HD;
    const float*  __restrict__ xk_r = xk + (size_t)bh * SEQ * HD;
    const ushort* __restrict__ xv_r = xv + (size_t)bh * SEQ * HD;

    const int tid  = threadIdx.x;
    const int w    = tid >> 6;
    const int lane = tid & 63;

    // ---- stage K (xor-swizzled 16B blocks, fp32) ----
    for (int idx = tid; idx < SEQ * 16; idx += 256) {
        const int k = idx >> 4, db = idx & 15;
        float4 kv = *(const float4*)(xk_r + k * HD + db * 4);
        const int sdb = db ^ (k & 7);
        *(float4*)&K_s[k * HD + sdb * 4] = kv;
    }
    // ---- stage V (bf16 -> fp32, linear) ----
    for (int idx = tid; idx < SEQ * 8; idx += 256) {
        const int k = idx >> 3, c = idx & 7;
        f32x8 f = unpk8v(*(const uint4*)(xv_r + k * HD + c * 8));
        *(float4*)&V_s[k * HD + c * 8 + 0] = make_float4(f[0], f[1], f[2], f[3]);
        *(float4*)&V_s[k * HD + c * 8 + 4] = make_float4(f[4], f[5], f[6], f[7]);
    }
    // ---- r_x/r_y: (S, 28) per table; r[q][e] = sum_{d<32} xq[q,d]*tab[e,d] ----
    for (int o = tid; o < SEQ * 2 * NE; o += 256) {
        const int q = o / (2 * NE);
        const int j = o % (2 * NE);
        const int isx = (j < NE);
        const int e = isx ? j : (j - NE);
        const float* qrow = xq_r + q * HD + (isx ? 0 : 32);
        const float* tab  = (isx ? q_tab_x : q_tab_y) + e * 32;
        float acc = 0.f;
#pragma unroll
        for (int d = 0; d < 32; d += 4) {
            float4 a = *(const float4*)(qrow + d);
            float4 t = *(const float4*)(tab + d);
            acc += a.x * t.x + a.y * t.y + a.z * t.z + a.w * t.w;
        }
        (isx ? rx_s : ry_s)[q * NE + e] = acc;
    }
    __syncthreads();

    const int k0 = lane, k1 = lane + 64, k2 = lane + 128, k3 = lane + 192;
    const bool v3 = (k3 < SEQ);
    const int k3c = v3 ? k3 : 0;
    const int swz = (lane & 7);   // k0..k3 differ by 64 -> same low-3 bits

    for (int q0 = w * 4; q0 < SEQ; q0 += 16) {
        // ---------------- QK^T for 4 query rows ----------------
        float acc[4][4];
#pragma unroll
        for (int qq = 0; qq < 4; qq++)
#pragma unroll
            for (int s = 0; s < 4; s++) acc[qq][s] = 0.f;

        const float* qps[4];
#pragma unroll
        for (int qq = 0; qq < 4; qq++) {
            int qi = q0 + qq; if (qi > SEQ - 1) qi = SEQ - 1;
            qps[qq] = xq_r + qi * HD;
        }
#pragma unroll
        for (int db = 0; db < 16; db++) {
            const int so = ((db ^ swz) << 2);
            float4 kv[4];
            kv[0] = *(const float4*)&K_s[k0 * HD + so];
            kv[1] = *(const float4*)&K_s[k1 * HD + so];
            kv[2] = *(const float4*)&K_s[k2 * HD + so];
            kv[3] = *(const float4*)&K_s[k3c * HD + so];
#pragma unroll
            for (int qq = 0; qq < 4; qq++) {
                float4 qv = *(const float4*)(qps[qq] + db * 4);
#pragma unroll
                for (int s = 0; s < 4; s++) {
                    acc[qq][s] = fmaf(qv.x, kv[s].x, acc[qq][s]);
                    acc[qq][s] = fmaf(qv.y, kv[s].y, acc[qq][s]);
                    acc[qq][s] = fmaf(qv.z, kv[s].z, acc[qq][s]);
                    acc[qq][s] = fmaf(qv.w, kv[s].w, acc[qq][s]);
                }
            }
        }

        // ---------------- softmax + histogram per query ----------------
#pragma unroll
        for (int qq = 0; qq < 4; qq++) {
            const int q = q0 + qq;
            if (q < SEQ) {
                const int* xd = x_dist + q * SEQ;
                const int* yd = y_dist + q * SEQ;
                const int e0x = xd[k0], e1x = xd[k1], e2x = xd[k2], e3x = xd[k3c];
                const int e0y = yd[k0], e1y = yd[k1], e2y = yd[k2], e3y = yd[k3c];
                const float* rx = rx_s + q * NE;
                const float* ry = ry_s + q * NE;
                const float l0 = (acc[qq][0] + rx[e0x] + ry[e0y]) * 0.125f;
                const float l1 = (acc[qq][1] + rx[e1x] + ry[e1y]) * 0.125f;
                const float l2 = (acc[qq][2] + rx[e2x] + ry[e2y]) * 0.125f;
                const float l3 = v3 ? (acc[qq][3] + rx[e3x] + ry[e3y]) * 0.125f : -1e30f;
                float mx = fmaxf(fmaxf(l0, l1), fmaxf(l2, l3));
#pragma unroll
                for (int off = 32; off >= 1; off >>= 1) mx = fmaxf(mx, __shfl_xor(mx, off));
                float p0 = __expf(l0 - mx), p1 = __expf(l1 - mx), p2 = __expf(l2 - mx);
                float p3 = v3 ? __expf(l3 - mx) : 0.f;
                float sm = p0 + p1 + p2 + p3;
#pragma unroll
                for (int off = 32; off >= 1; off >>= 1) sm += __shfl_xor(sm, off);
                const float inv = 1.f / sm;
                p0 *= inv; p1 *= inv; p2 *= inv; p3 *= inv;

                if (lane < 2 * NE) h_s[w][qq][lane] = 0.f;
                p_s[w][qq][k0] = p0;
                p_s[w][qq][k1] = p1;
                p_s[w][qq][k2] = p2;
                if (v3) p_s[w][qq][k3] = p3;
                atomicAdd(&h_s[w][qq][e0x], p0);
                atomicAdd(&h_s[w][qq][NE + e0y], p0);
                atomicAdd(&h_s[w][qq][e1x], p1);
                atomicAdd(&h_s[w][qq][NE + e1y], p1);
                atomicAdd(&h_s[w][qq][e2x], p2);
                atomicAdd(&h_s[w][qq][NE + e2y], p2);
                if (v3) {
                    atomicAdd(&h_s[w][qq][e3x], p3);
                    atomicAdd(&h_s[w][qq][NE + e3y], p3);
                }
            }
        }

        // ---------------- PV (4 queries, lane = (d4, kk) split) ----------------
        const int d4 = (lane & 15) * 4;
        const int kk = lane >> 4;
        float4 o4[4];
#pragma unroll
        for (int qq = 0; qq < 4; qq++) o4[qq] = make_float4(0.f, 0.f, 0.f, 0.f);

        for (int kb = 0; kb < SEQ; kb += 4) {
            const int k  = kb + kk;
            const bool ok = (k < SEQ);
            const int kc = ok ? k : 0;
            float4 vv = *(const float4*)&V_s[kc * HD + d4];
#pragma unroll
            for (int qq = 0; qq < 4; qq++) {
                const float p = ok ? p_s[w][qq][k] : 0.f;
                o4[qq].x = fmaf(p, vv.x, o4[qq].x);
                o4[qq].y = fmaf(p, vv.y, o4[qq].y);
                o4[qq].z = fmaf(p, vv.z, o4[qq].z);
                o4[qq].w = fmaf(p, vv.w, o4[qq].w);
            }
        }
#pragma unroll
        for (int qq = 0; qq < 4; qq++) {
            o4[qq].x += __shfl_xor(o4[qq].x, 16); o4[qq].x += __shfl_xor(o4[qq].x, 32);
            o4[qq].y += __shfl_xor(o4[qq].y, 16); o4[qq].y += __shfl_xor(o4[qq].y, 32);
            o4[qq].z += __shfl_xor(o4[qq].z, 16); o4[qq].z += __shfl_xor(o4[qq].z, 32);
            o4[qq].w += __shfl_xor(o4[qq].w, 16); o4[qq].w += __shfl_xor(o4[qq].w, 32);
        }

        if (kk == 0) {
            const bool isx = (d4 < 32);
            const int dl = d4 & 31;
            const float* tab = (isx ? v_tab_x : v_tab_y) + dl;
#pragma unroll
            for (int e = 0; e < NE; e++) {
                float4 tv = *(const float4*)(tab + e * 32);
#pragma unroll
                for (int qq = 0; qq < 4; qq++) {
                    const float hh = h_s[w][qq][(isx ? 0 : NE) + e];
                    o4[qq].x = fmaf(hh, tv.x, o4[qq].x);
                    o4[qq].y = fmaf(hh, tv.y, o4[qq].y);
                    o4[qq].z = fmaf(hh, tv.z, o4[qq].z);
                    o4[qq].w = fmaf(hh, tv.w, o4[qq].w);
                }
            }
#pragma unroll
            for (int qq = 0; qq < 4; qq++) {
                const int q = q0 + qq;
                if (q < SEQ) {
                    unsigned r0 = ((unsigned)f2bf(o4[qq].y) << 16) | f2bf(o4[qq].x);
                    unsigned r1 = ((unsigned)f2bf(o4[qq].w) << 16) | f2bf(o4[qq].z);
                    uint2 pk = { r0, r1 };
                    // (b, s, h, d) = row-major (M, EMB) for the output projection
                    *(uint2*)(ao + (((size_t)b * SEQ + q) * NH + h) * HD + d4) = pk;
                }
            }
        }
    }
}

extern "C" void kernel_launch(void* const* d_in, const int* in_sizes, int n_in,
                              void* d_out, int out_size, void* d_ws, size_t ws_size,
                              hipStream_t stream) {
    const float* x       = (const float*)d_in[0];
    const float* Wq      = (const float*)d_in[1];
    const float* bq      = (const float*)d_in[2];
    const float* Wk      = (const float*)d_in[3];
    const float* bk      = (const float*)d_in[4];
    const float* Wv      = (const float*)d_in[5];
    const float* bv      = (const float*)d_in[6];
    const float* Wo      = (const float*)d_in[7];
    const float* bo      = (const float*)d_in[8];
    const float* q_tab_x = (const float*)d_in[9];
    const float* q_tab_y = (const float*)d_in[10];
    const float* v_tab_x = (const float*)d_in[11];
    const float* v_tab_y = (const float*)d_in[12];
    const int*   x_dist  = (const int*)d_in[13];
    const int*   y_dist  = (const int*)d_in[14];
    float* out = (float*)d_out;

    const int M  = in_sizes[0] / EMB;   // 12608
    const int Bc = M / SEQ;             // 64

    // ws carve (140.3 MB total, all segments 16B-aligned):
    // xb(bf16 M*E) | wqkv(bf16 3E*E) | wob(bf16 E*E) | qf(f32) | kf(f32) | vb(bf16) | ao(bf16)
    ushort* xb   = (ushort*)d_ws;
    ushort* wqkv = xb   + (size_t)M * EMB;
    ushort* wob  = wqkv + (size_t)3 * EMB * EMB;
    float*  qf   = (float*)(wob + (size_t)EMB * EMB);
    float*  kf   = qf + (size_t)M * EMB;
    ushort* vb   = (ushort*)(kf + (size_t)M * EMB);
    ushort* aob  = vb + (size_t)M * EMB;

    const int n4x = M * EMB / 4;
    cvt_k<<<dim3((n4x + 255) / 256), dim3(256), 0, stream>>>(x, xb, n4x);
    cvt_w4<<<dim3(2304), dim3(256), 0, stream>>>(Wq, Wk, Wv, Wo, wqkv, wob);

    mfma_gemm<0><<<dim3((M + 127) / 128, 18), dim3(256), 0, stream>>>(
        xb, wqkv, bq, bk, bv, qf, kf, vb, nullptr, M);

    attn_k<<<dim3(Bc * NH), dim3(256), 0, stream>>>(qf, kf, vb, q_tab_x, q_tab_y,
                                                    v_tab_x, v_tab_y, x_dist, y_dist, aob);

    mfma_gemm<1><<<dim3((M + 127) / 128, 6), dim3(256), 0, stream>>>(
        aob, wob, bo, bo, bo, nullptr, nullptr, nullptr, out, M);
}